// Round 4
// baseline (646.550 us; speedup 1.0000x reference)
//
#include <hip/hip_runtime.h>
#include <hip/hip_fp16.h>
#include <math.h>

#define NPTS 80000
#define NBH 32
#define KP 15
#define CIN 128
#define COUT 256
#define D2 64
#define INFL 0.4f
#define EPS 1e-5f
#define SLOPE 0.2f

typedef __attribute__((ext_vector_type(8))) short short8;
typedef __attribute__((ext_vector_type(4))) float f32x4;

union U8 { uint u[4]; short8 s; uint4 v; };

__device__ inline ushort f2b(float x) {
  unsigned u = __float_as_uint(x);
  return (ushort)((u + 0x7FFFu + ((u >> 16) & 1u)) >> 16);  // RNE
}
__device__ inline float b2f(ushort v) { return __uint_as_float(((unsigned)v) << 16); }
__device__ inline uint packbf(float a, float b) {
  return (uint)f2b(a) | ((uint)f2b(b) << 16);
}
__device__ inline float h2f(ushort u) {
  __half_raw r; r.x = u;
  return __half2float(__half(r));
}

// ---------------- prep: rdiff (f16 neighbor offsets) + weights bf16 swizzled to MFMA B order
// B fragment order: Bsw[chunk][ctile][nn][q][j] <- B[k][n], k=chunk*32+q*8+j, n=ctile*16+nn
__global__ __launch_bounds__(256) void k_prep(const float* __restrict__ xyz,
                                              const int* __restrict__ nidx,
                                              const float* __restrict__ W1,
                                              const float* __restrict__ W2,
                                              const float* __restrict__ Wsc,
                                              const float* __restrict__ kw,
                                              ushort* __restrict__ rdiff,
                                              ushort* __restrict__ w1s,
                                              ushort* __restrict__ w2s,
                                              ushort* __restrict__ wscs,
                                              ushort* __restrict__ kws) {
  const int NPAIR = NPTS * NBH;  // 2,560,000
  const int TOT = NPAIR + 118784;
  int stride = gridDim.x * 256;
  for (int i = blockIdx.x * 256 + threadIdx.x; i < TOT; i += stride) {
    if (i < NPAIR) {
      int n = i >> 5;
      int nb = nidx[i];
      float rx = xyz[nb * 3 + 0] - xyz[n * 3 + 0];
      float ry = xyz[nb * 3 + 1] - xyz[n * 3 + 1];
      float rz = xyz[nb * 3 + 2] - xyz[n * 3 + 2];
      __half hx = __float2half(rx), hy = __float2half(ry), hz = __float2half(rz);
      rdiff[(size_t)i * 3 + 0] = __half_raw(hx).x;
      rdiff[(size_t)i * 3 + 1] = __half_raw(hy).x;
      rdiff[(size_t)i * 3 + 2] = __half_raw(hz).x;
    } else {
      int j = i - NPAIR;
      const float* src;
      ushort* dst;
      int logN;
      if (j < 8192)       { src = W1;  dst = w1s;  logN = 6; }
      else if (j < 24576) { j -= 8192;  src = W2;  dst = w2s;  logN = 8; }
      else if (j < 57344) { j -= 24576; src = Wsc; dst = wscs; logN = 8; }
      else                { j -= 57344; src = kw;  dst = kws;  logN = 6; }
      int N = 1 << logN, NT = N >> 4;
      int k = j >> logN, n = j & (N - 1);
      int dsti = ((k >> 5) * NT + (n >> 4)) * 512 + (n & 15) * 32 + ((k >> 3) & 3) * 8 + (k & 7);
      dst[dsti] = f2b(src[j]);
    }
  }
}

// ---------------- MFMA GEMM, f32 A (in-reg bf16 cvt), bf16 out, inline col-stats
template <int NCOLS>
__global__ __launch_bounds__(256) void k_gemm_f32a(const float* __restrict__ A,
                                                   const ushort* __restrict__ Bsw,
                                                   ushort* __restrict__ Cb, int K,
                                                   float* __restrict__ S,
                                                   float* __restrict__ SS) {
  constexpr int NT = NCOLS / 16;
  int tid = threadIdx.x;
  int wave = tid >> 6, lane = tid & 63;
  int nn = lane & 15, q = lane >> 4;
  int row0 = blockIdx.x * 64 + wave * 16;
  f32x4 acc[NT];
#pragma unroll
  for (int c = 0; c < NT; ++c) acc[c] = (f32x4){0.f, 0.f, 0.f, 0.f};
  const float* ap = A + (size_t)(row0 + nn) * K + q * 8;
  int nch = K >> 5;
  for (int ch = 0; ch < nch; ++ch) {
    float4 f0 = *reinterpret_cast<const float4*>(ap + ch * 32);
    float4 f1 = *reinterpret_cast<const float4*>(ap + ch * 32 + 4);
    U8 af;
    af.u[0] = packbf(f0.x, f0.y); af.u[1] = packbf(f0.z, f0.w);
    af.u[2] = packbf(f1.x, f1.y); af.u[3] = packbf(f1.z, f1.w);
    const ushort* bp = Bsw + (size_t)ch * NT * 512 + nn * 32 + q * 8;
#pragma unroll
    for (int c = 0; c < NT; ++c) {
      U8 bf; bf.v = *reinterpret_cast<const uint4*>(bp + c * 512);
      acc[c] = __builtin_amdgcn_mfma_f32_16x16x32_bf16(af.s, bf.s, acc[c], 0, 0, 0);
    }
  }
#pragma unroll
  for (int c = 0; c < NT; ++c) {
    float s = 0.f, s2 = 0.f;
#pragma unroll
    for (int r = 0; r < 4; ++r) {
      float v = acc[c][r];
      s += v; s2 += v * v;
      Cb[(size_t)(row0 + q * 4 + r) * NCOLS + c * 16 + nn] = f2b(v);
    }
    s += __shfl_xor(s, 16);  s += __shfl_xor(s, 32);
    s2 += __shfl_xor(s2, 16); s2 += __shfl_xor(s2, 32);
    if (q == 0) {
      atomicAdd(&S[c * 16 + nn], s);
      atomicAdd(&SS[c * 16 + nn], s2);
    }
  }
}

// ---------------- bn + leaky on bf16 [N,64] -> bf16
__global__ __launch_bounds__(256) void k_normb(const ushort* __restrict__ X,
                                               const float* __restrict__ sum,
                                               const float* __restrict__ sumsq,
                                               const float* __restrict__ g,
                                               const float* __restrict__ b,
                                               ushort* __restrict__ out) {
  __shared__ float sc[64], sh[64];
  int tid = threadIdx.x;
  if (tid < 64) {
    float m = sum[tid] * (1.0f / NPTS);
    float v = sumsq[tid] * (1.0f / NPTS) - m * m;
    float s = g[tid] * rsqrtf(v + EPS);
    sc[tid] = s;
    sh[tid] = b[tid] - m * s;
  }
  __syncthreads();
  const int units = NPTS * 8;  // short8 units
  int stride = gridDim.x * 256;
  for (int i = blockIdx.x * 256 + tid; i < units; i += stride) {
    short8 v = reinterpret_cast<const short8*>(X)[i];
    int cb = (i & 7) * 8;
    short8 o;
#pragma unroll
    for (int k = 0; k < 8; ++k) {
      float a = b2f((ushort)v[k]) * sc[cb + k] + sh[cb + k];
      a = a > 0.f ? a : SLOPE * a;
      o[k] = (short)f2b(a);
    }
    reinterpret_cast<short8*>(out)[i] = o;
  }
}

// ---------------- fused KPConv + unary2 + Y3 stats. 256 thr / 4 waves / 16 points.
__global__ __launch_bounds__(256, 3) void k_kpfused(const ushort* __restrict__ X1b,
                                                    const ushort* __restrict__ rdiff,
                                                    const int* __restrict__ nidx,
                                                    const float* __restrict__ kpp,
                                                    const ushort* __restrict__ kws,
                                                    const ushort* __restrict__ w2s,
                                                    ushort* __restrict__ Y3b,
                                                    float* __restrict__ S3,
                                                    float* __restrict__ SS3) {
  __shared__ uint s_xi[4][1280];     // per-wave: [d 0..63][t-col 0..15 + pad4], h-pair interleave
  __shared__ ushort s_fk[30 * 512];  // fk in stage-2 A layout
  __shared__ ushort s_y2[2 * 512];   // Y2 in u2 A layout
  int tid = threadIdx.x;
  int w = tid >> 6, lane = tid & 63;
  int q = lane >> 4, nn = lane & 15;
  int n_base = blockIdx.x * 16;
  int kidx = nn < 15 ? nn : 0;
  float kpx = kpp[kidx * 3 + 0], kpy = kpp[kidx * 3 + 1], kpz = kpp[kidx * 3 + 2];
  uint* sx = s_xi[w];

  for (int p = 0; p < 4; ++p) {
    int n = n_base + w * 4 + p;
    // ---- gather 32 neighbor rows, interleave h-pairs into d-major LDS
#pragma unroll
    for (int i = 0; i < 4; ++i) {
      int t = i * 4 + q;
      int nb0 = nidx[n * NBH + 2 * t];
      int nb1 = nidx[n * NBH + 2 * t + 1];
      uint2 a = *reinterpret_cast<const uint2*>(X1b + (size_t)nb0 * 64 + nn * 4);
      uint2 b = *reinterpret_cast<const uint2*>(X1b + (size_t)nb1 * 64 + nn * 4);
      uint d0 = (a.x & 0xFFFFu) | (b.x << 16);
      uint d1 = (a.x >> 16) | (b.x & 0xFFFF0000u);
      uint d2 = (a.y & 0xFFFFu) | (b.y << 16);
      uint d3 = (a.y >> 16) | (b.y & 0xFFFF0000u);
      int tp = t ^ ((nn & 3) << 2);
      sx[(nn * 4 + 0) * 20 + tp] = d0;
      sx[(nn * 4 + 1) * 20 + tp] = d1;
      sx[(nn * 4 + 2) * 20 + tp] = d2;
      sx[(nn * 4 + 3) * 20 + tp] = d3;
    }
    // ---- influence-weight A fragment from precomputed f16 rdiff
    const ushort* rp = rdiff + ((size_t)n * NBH + q * 8) * 3;
    uint4 r0 = *reinterpret_cast<const uint4*>(rp);
    uint4 r1 = *reinterpret_cast<const uint4*>(rp + 8);
    uint4 r2 = *reinterpret_cast<const uint4*>(rp + 16);
    uint wv[12] = {r0.x, r0.y, r0.z, r0.w, r1.x, r1.y, r1.z, r1.w, r2.x, r2.y, r2.z, r2.w};
    float wgt[8];
#pragma unroll
    for (int j = 0; j < 8; ++j) {
      int i0 = 3 * j, i1 = 3 * j + 1, i2 = 3 * j + 2;
      float rx = h2f((i0 & 1) ? (ushort)(wv[i0 >> 1] >> 16) : (ushort)(wv[i0 >> 1] & 0xFFFF));
      float ry = h2f((i1 & 1) ? (ushort)(wv[i1 >> 1] >> 16) : (ushort)(wv[i1 >> 1] & 0xFFFF));
      float rz = h2f((i2 & 1) ? (ushort)(wv[i2 >> 1] >> 16) : (ushort)(wv[i2 >> 1] & 0xFFFF));
      float dx = rx - kpx, dy = ry - kpy, dz = rz - kpz;
      float dist = sqrtf(dx * dx + dy * dy + dz * dz);
      float t = fmaxf(1.0f - dist * (1.0f / INFL), 0.0f);
      wgt[j] = (nn == 15) ? 0.f : t;
    }
    U8 af;
#pragma unroll
    for (int j2 = 0; j2 < 4; ++j2) af.u[j2] = packbf(wgt[2 * j2], wgt[2 * j2 + 1]);
    // ---- stage-1 MFMA: fk[kpt][d] = sum_h w[h][kpt] * x[h][d]
    int m = w * 4 + p;
#pragma unroll
    for (int c = 0; c < 4; ++c) {
      int d = c * 16 + nn;
      int db3 = nn >> 2;
      U8 bf;
      bf.v = *reinterpret_cast<const uint4*>(&sx[d * 20 + ((q ^ db3) << 2)]);
      f32x4 acc = __builtin_amdgcn_mfma_f32_16x16x32_bf16(af.s, bf.s,
                                                          (f32x4){0.f, 0.f, 0.f, 0.f}, 0, 0, 0);
#pragma unroll
      for (int r = 0; r < 4; ++r) {
        int kpt = q * 4 + r;
        if (kpt < 15) {
          int kap = kpt * 64 + d;
          int ch = kap >> 5, t2 = kap & 31;
          int tp2 = t2 ^ (((ch >> 3) & 3) << 3);
          s_fk[ch * 512 + m * 32 + tp2] = f2b(acc[r]);
        }
      }
    }
  }
  __syncthreads();

  // ---- stage-2: Y2[16x64] = FK[16x960] * kw; wave w owns col tile w
  f32x4 acc2 = (f32x4){0.f, 0.f, 0.f, 0.f};
  for (int ch = 0; ch < 30; ++ch) {
    int key = (ch >> 3) & 3;
    U8 a, b;
    a.v = *reinterpret_cast<const uint4*>(&s_fk[ch * 512 + nn * 32 + ((q ^ key) << 3)]);
    b.v = *reinterpret_cast<const uint4*>(kws + (size_t)ch * 2048 + w * 512 + nn * 32 + q * 8);
    acc2 = __builtin_amdgcn_mfma_f32_16x16x32_bf16(a.s, b.s, acc2, 0, 0, 0);
  }
  {
    int e = w * 16 + nn;
    int ch2 = e >> 5, t = e & 31;
#pragma unroll
    for (int r = 0; r < 4; ++r) {
      int mm = q * 4 + r;
      int tp = t ^ (((mm >> 2) & 3) << 3);
      s_y2[ch2 * 512 + mm * 32 + tp] = f2b(acc2[r]);
    }
  }
  __syncthreads();

  // ---- unary_2: Y3[16x256] = Y2 * W2; wave w owns col tiles w*4..w*4+3; + stats
  U8 a0, a1;
  {
    int key = (nn >> 2) & 3;
    a0.v = *reinterpret_cast<const uint4*>(&s_y2[0 * 512 + nn * 32 + ((q ^ key) << 3)]);
    a1.v = *reinterpret_cast<const uint4*>(&s_y2[1 * 512 + nn * 32 + ((q ^ key) << 3)]);
  }
#pragma unroll
  for (int t4 = 0; t4 < 4; ++t4) {
    int ct = w * 4 + t4;
    U8 b0, b1;
    b0.v = *reinterpret_cast<const uint4*>(w2s + (0 * 16 + ct) * 512 + nn * 32 + q * 8);
    b1.v = *reinterpret_cast<const uint4*>(w2s + (1 * 16 + ct) * 512 + nn * 32 + q * 8);
    f32x4 a = __builtin_amdgcn_mfma_f32_16x16x32_bf16(a0.s, b0.s, (f32x4){0.f, 0.f, 0.f, 0.f}, 0, 0, 0);
    a = __builtin_amdgcn_mfma_f32_16x16x32_bf16(a1.s, b1.s, a, 0, 0, 0);
    float s = a[0] + a[1] + a[2] + a[3];
    float s2 = a[0] * a[0] + a[1] * a[1] + a[2] * a[2] + a[3] * a[3];
    s += __shfl_xor(s, 16);  s += __shfl_xor(s, 32);
    s2 += __shfl_xor(s2, 16); s2 += __shfl_xor(s2, 32);
    if (q == 0) {
      atomicAdd(&S3[ct * 16 + nn], s);
      atomicAdd(&SS3[ct * 16 + nn], s2);
    }
#pragma unroll
    for (int r = 0; r < 4; ++r)
      Y3b[(size_t)(n_base + q * 4 + r) * 256 + ct * 16 + nn] = f2b(a[r]);
  }
}

// ---------------- final: out = leaky(bn(Y3b)) + bn(YSCb), f32 out
__global__ __launch_bounds__(256) void k_final(const ushort* __restrict__ Y3,
                                               const ushort* __restrict__ YSC,
                                               const float* __restrict__ s3,
                                               const float* __restrict__ ss3,
                                               const float* __restrict__ g2,
                                               const float* __restrict__ b2,
                                               const float* __restrict__ ssc,
                                               const float* __restrict__ sssc,
                                               const float* __restrict__ gsc,
                                               const float* __restrict__ bsc,
                                               float* __restrict__ out) {
  __shared__ float sc3[256], sh3[256], scc[256], shc[256];
  int tid = threadIdx.x;
  {
    float m = s3[tid] * (1.0f / NPTS);
    float v = ss3[tid] * (1.0f / NPTS) - m * m;
    float s = g2[tid] * rsqrtf(v + EPS);
    sc3[tid] = s;
    sh3[tid] = b2[tid] - m * s;
    m = ssc[tid] * (1.0f / NPTS);
    v = sssc[tid] * (1.0f / NPTS) - m * m;
    s = gsc[tid] * rsqrtf(v + EPS);
    scc[tid] = s;
    shc[tid] = bsc[tid] - m * s;
  }
  __syncthreads();
  const int units = NPTS * 32;  // short8 units per matrix
  int stride = gridDim.x * 256;
  for (int i = blockIdx.x * 256 + tid; i < units; i += stride) {
    short8 a = reinterpret_cast<const short8*>(Y3)[i];
    short8 b = reinterpret_cast<const short8*>(YSC)[i];
    int cb = (i & 31) * 8;
    float o[8];
#pragma unroll
    for (int k = 0; k < 8; ++k) {
      float x = b2f((ushort)a[k]) * sc3[cb + k] + sh3[cb + k];
      x = x > 0.f ? x : SLOPE * x;
      o[k] = x + b2f((ushort)b[k]) * scc[cb + k] + shc[cb + k];
    }
    float4* O4 = reinterpret_cast<float4*>(out + (size_t)i * 8);
    O4[0] = make_float4(o[0], o[1], o[2], o[3]);
    O4[1] = make_float4(o[4], o[5], o[6], o[7]);
  }
}

extern "C" void kernel_launch(void* const* d_in, const int* in_sizes, int n_in,
                              void* d_out, int out_size, void* d_ws, size_t ws_size,
                              hipStream_t stream) {
  const float* feats = (const float*)d_in[0];
  const float* xyz   = (const float*)d_in[1];
  const int* nidx    = (const int*)d_in[3];
  const float* W1    = (const float*)d_in[4];
  const float* g1    = (const float*)d_in[5];
  const float* b1    = (const float*)d_in[6];
  const float* kpp   = (const float*)d_in[7];
  const float* kw    = (const float*)d_in[8];
  const float* W2    = (const float*)d_in[9];
  const float* g2    = (const float*)d_in[10];
  const float* b2    = (const float*)d_in[11];
  const float* Wsc   = (const float*)d_in[12];
  const float* gsc   = (const float*)d_in[13];
  const float* bsc   = (const float*)d_in[14];
  float* out = (float*)d_out;

  // ws layout (bytes): X1r 10.24M | X1b 10.24M | Y3b 40.96M | YSCb 40.96M | rdiff 15.36M | weights | stats
  char* ws = (char*)d_ws;
  ushort* X1r   = (ushort*)ws;
  ushort* X1b   = (ushort*)(ws + 10240000);
  ushort* Y3b   = (ushort*)(ws + 20480000);
  ushort* YSCb  = (ushort*)(ws + 61440000);
  ushort* rdiff = (ushort*)(ws + 102400000);
  ushort* w1s   = (ushort*)(ws + 117760000);
  ushort* w2s   = (ushort*)(ws + 117776384);
  ushort* wscs  = (ushort*)(ws + 117809152);
  ushort* kws   = (ushort*)(ws + 117874688);
  float*  ST    = (float*)(ws + 117997568);
  float *S1 = ST, *SS1 = ST + 64;
  float *S3 = ST + 128, *SS3 = ST + 384;
  float *SSC = ST + 640, *SSSC = ST + 896;

  hipMemsetAsync(ST, 0, 1152 * sizeof(float), stream);
  k_prep<<<4096, 256, 0, stream>>>(xyz, nidx, W1, W2, Wsc, kw, rdiff, w1s, w2s, wscs, kws);
  // unary_1 (+S1 stats)
  k_gemm_f32a<64><<<1250, 256, 0, stream>>>(feats, w1s, X1r, 128, S1, SS1);
  k_normb<<<512, 256, 0, stream>>>(X1r, S1, SS1, g1, b1, X1b);
  // shortcut (+SSC stats)
  k_gemm_f32a<256><<<1250, 256, 0, stream>>>(feats, wscs, YSCb, 128, SSC, SSSC);
  // fused KPConv + unary_2 (+S3 stats)
  k_kpfused<<<NPTS / 16, 256, 0, stream>>>(X1b, rdiff, nidx, kpp, kws, w2s, Y3b, S3, SS3);
  // out = leaky(bn(Y3b)) + bn(YSCb)
  k_final<<<1024, 256, 0, stream>>>(Y3b, YSCb, S3, SS3, g2, b2, SSC, SSSC, gsc, bsc, out);
}

// Round 5
// 389.206 us; speedup vs baseline: 1.6612x; 1.6612x over previous
//
#include <hip/hip_runtime.h>
#include <hip/hip_fp16.h>
#include <math.h>

#define NPTS 80000
#define NBH 32
#define KP 15
#define CIN 128
#define COUT 256
#define D2 64
#define INFL 0.4f
#define EPS 1e-5f
#define SLOPE 0.2f

typedef __attribute__((ext_vector_type(8))) short short8;
typedef __attribute__((ext_vector_type(4))) float f32x4;

union U8 { uint u[4]; short8 s; uint4 v; };

__device__ inline ushort f2b(float x) {
  unsigned u = __float_as_uint(x);
  return (ushort)((u + 0x7FFFu + ((u >> 16) & 1u)) >> 16);  // RNE
}
__device__ inline float b2f(ushort v) { return __uint_as_float(((unsigned)v) << 16); }
__device__ inline uint packbf(float a, float b) {
  return (uint)f2b(a) | ((uint)f2b(b) << 16);
}
__device__ inline float h2f(ushort u) {
  __half_raw r; r.x = u;
  return __half2float(__half(r));
}

// ---------------- prep: rdiff (f16 neighbor offsets) + weights bf16 swizzled to MFMA B order
// B fragment order: Bsw[chunk][ctile][nn][q][j] <- B[k][n], k=chunk*32+q*8+j, n=ctile*16+nn
__global__ __launch_bounds__(256) void k_prep(const float* __restrict__ xyz,
                                              const int* __restrict__ nidx,
                                              const float* __restrict__ W1,
                                              const float* __restrict__ W2,
                                              const float* __restrict__ Wsc,
                                              const float* __restrict__ kw,
                                              ushort* __restrict__ rdiff,
                                              ushort* __restrict__ w1s,
                                              ushort* __restrict__ w2s,
                                              ushort* __restrict__ wscs,
                                              ushort* __restrict__ kws) {
  const int NPAIR = NPTS * NBH;  // 2,560,000
  const int TOT = NPAIR + 118784;
  int stride = gridDim.x * 256;
  for (int i = blockIdx.x * 256 + threadIdx.x; i < TOT; i += stride) {
    if (i < NPAIR) {
      int n = i >> 5;
      int nb = nidx[i];
      float rx = xyz[nb * 3 + 0] - xyz[n * 3 + 0];
      float ry = xyz[nb * 3 + 1] - xyz[n * 3 + 1];
      float rz = xyz[nb * 3 + 2] - xyz[n * 3 + 2];
      __half hx = __float2half(rx), hy = __float2half(ry), hz = __float2half(rz);
      rdiff[(size_t)i * 3 + 0] = __half_raw(hx).x;
      rdiff[(size_t)i * 3 + 1] = __half_raw(hy).x;
      rdiff[(size_t)i * 3 + 2] = __half_raw(hz).x;
    } else {
      int j = i - NPAIR;
      const float* src;
      ushort* dst;
      int logN;
      if (j < 8192)       { src = W1;  dst = w1s;  logN = 6; }
      else if (j < 24576) { j -= 8192;  src = W2;  dst = w2s;  logN = 8; }
      else if (j < 57344) { j -= 24576; src = Wsc; dst = wscs; logN = 8; }
      else                { j -= 57344; src = kw;  dst = kws;  logN = 6; }
      int N = 1 << logN, NT = N >> 4;
      int k = j >> logN, n = j & (N - 1);
      int dsti = ((k >> 5) * NT + (n >> 4)) * 512 + (n & 15) * 32 + ((k >> 3) & 3) * 8 + (k & 7);
      dst[dsti] = f2b(src[j]);
    }
  }
}

// ---------------- MFMA GEMM, f32 A (in-reg bf16 cvt), bf16 out. No stats.
template <int NCOLS>
__global__ __launch_bounds__(256) void k_gemm_f32a(const float* __restrict__ A,
                                                   const ushort* __restrict__ Bsw,
                                                   ushort* __restrict__ Cb, int K) {
  constexpr int NT = NCOLS / 16;
  int tid = threadIdx.x;
  int wave = tid >> 6, lane = tid & 63;
  int nn = lane & 15, q = lane >> 4;
  int row0 = blockIdx.x * 64 + wave * 16;
  f32x4 acc[NT];
#pragma unroll
  for (int c = 0; c < NT; ++c) acc[c] = (f32x4){0.f, 0.f, 0.f, 0.f};
  const float* ap = A + (size_t)(row0 + nn) * K + q * 8;
  int nch = K >> 5;
  for (int ch = 0; ch < nch; ++ch) {
    float4 f0 = *reinterpret_cast<const float4*>(ap + ch * 32);
    float4 f1 = *reinterpret_cast<const float4*>(ap + ch * 32 + 4);
    U8 af;
    af.u[0] = packbf(f0.x, f0.y); af.u[1] = packbf(f0.z, f0.w);
    af.u[2] = packbf(f1.x, f1.y); af.u[3] = packbf(f1.z, f1.w);
    const ushort* bp = Bsw + (size_t)ch * NT * 512 + nn * 32 + q * 8;
#pragma unroll
    for (int c = 0; c < NT; ++c) {
      U8 bf; bf.v = *reinterpret_cast<const uint4*>(bp + c * 512);
      acc[c] = __builtin_amdgcn_mfma_f32_16x16x32_bf16(af.s, bf.s, acc[c], 0, 0, 0);
    }
  }
#pragma unroll
  for (int c = 0; c < NT; ++c)
#pragma unroll
    for (int r = 0; r < 4; ++r)
      Cb[(size_t)(row0 + q * 4 + r) * NCOLS + c * 16 + nn] = f2b(acc[c][r]);
}

// ---------------- per-column sum/sumsq over bf16 matrix (vectorized, LDS reduce, 256 blocks)
__global__ __launch_bounds__(256) void k_colstats_b16(const ushort* __restrict__ X, int units,
                                                      int cols, float* __restrict__ sum,
                                                      float* __restrict__ sumsq) {
  __shared__ float ls[2048], ls2[2048];
  int tid = threadIdx.x;
  int stride = gridDim.x * 256;  // divisible by cols/8
  float s[8], s2[8];
#pragma unroll
  for (int k = 0; k < 8; ++k) { s[k] = 0.f; s2[k] = 0.f; }
  for (int i = blockIdx.x * 256 + tid; i < units; i += stride) {
    short8 v = reinterpret_cast<const short8*>(X)[i];
#pragma unroll
    for (int k = 0; k < 8; ++k) {
      float f = b2f((ushort)v[k]);
      s[k] += f;
      s2[k] += f * f;
    }
  }
#pragma unroll
  for (int k = 0; k < 8; ++k) { ls[tid * 8 + k] = s[k]; ls2[tid * 8 + k] = s2[k]; }
  __syncthreads();
  if (tid < cols) {
    int P = cols >> 3;
    float a = 0.f, a2 = 0.f;
    for (int t = (tid >> 3); t < 256; t += P) {
      a += ls[t * 8 + (tid & 7)];
      a2 += ls2[t * 8 + (tid & 7)];
    }
    atomicAdd(&sum[tid], a);
    atomicAdd(&sumsq[tid], a2);
  }
}

// ---------------- bn + leaky on bf16 [N,64] -> bf16
__global__ __launch_bounds__(256) void k_normb(const ushort* __restrict__ X,
                                               const float* __restrict__ sum,
                                               const float* __restrict__ sumsq,
                                               const float* __restrict__ g,
                                               const float* __restrict__ b,
                                               ushort* __restrict__ out) {
  __shared__ float sc[64], sh[64];
  int tid = threadIdx.x;
  if (tid < 64) {
    float m = sum[tid] * (1.0f / NPTS);
    float v = sumsq[tid] * (1.0f / NPTS) - m * m;
    float s = g[tid] * rsqrtf(v + EPS);
    sc[tid] = s;
    sh[tid] = b[tid] - m * s;
  }
  __syncthreads();
  const int units = NPTS * 8;  // short8 units
  int stride = gridDim.x * 256;
  for (int i = blockIdx.x * 256 + tid; i < units; i += stride) {
    short8 v = reinterpret_cast<const short8*>(X)[i];
    int cb = (i & 7) * 8;
    short8 o;
#pragma unroll
    for (int k = 0; k < 8; ++k) {
      float a = b2f((ushort)v[k]) * sc[cb + k] + sh[cb + k];
      a = a > 0.f ? a : SLOPE * a;
      o[k] = (short)f2b(a);
    }
    reinterpret_cast<short8*>(out)[i] = o;
  }
}

// ---------------- fused KPConv + unary2. 256 thr / 4 waves / 16 points. No stats.
__global__ __launch_bounds__(256, 3) void k_kpfused(const ushort* __restrict__ X1b,
                                                    const ushort* __restrict__ rdiff,
                                                    const int* __restrict__ nidx,
                                                    const float* __restrict__ kpp,
                                                    const ushort* __restrict__ kws,
                                                    const ushort* __restrict__ w2s,
                                                    ushort* __restrict__ Y3b) {
  __shared__ uint s_xi[4][1280];     // per-wave: [d 0..63][t-col 0..15 + pad4], h-pair interleave
  __shared__ ushort s_fk[30 * 512];  // fk in stage-2 A layout
  __shared__ ushort s_y2[2 * 512];   // Y2 in u2 A layout
  int tid = threadIdx.x;
  int w = tid >> 6, lane = tid & 63;
  int q = lane >> 4, nn = lane & 15;
  int n_base = blockIdx.x * 16;
  int kidx = nn < 15 ? nn : 0;
  float kpx = kpp[kidx * 3 + 0], kpy = kpp[kidx * 3 + 1], kpz = kpp[kidx * 3 + 2];
  uint* sx = s_xi[w];

  for (int p = 0; p < 4; ++p) {
    int n = n_base + w * 4 + p;
    // ---- gather 32 neighbor rows, interleave h-pairs into d-major LDS
#pragma unroll
    for (int i = 0; i < 4; ++i) {
      int t = i * 4 + q;
      int nb0 = nidx[n * NBH + 2 * t];
      int nb1 = nidx[n * NBH + 2 * t + 1];
      uint2 a = *reinterpret_cast<const uint2*>(X1b + (size_t)nb0 * 64 + nn * 4);
      uint2 b = *reinterpret_cast<const uint2*>(X1b + (size_t)nb1 * 64 + nn * 4);
      uint d0 = (a.x & 0xFFFFu) | (b.x << 16);
      uint d1 = (a.x >> 16) | (b.x & 0xFFFF0000u);
      uint d2 = (a.y & 0xFFFFu) | (b.y << 16);
      uint d3 = (a.y >> 16) | (b.y & 0xFFFF0000u);
      int tp = t ^ ((nn & 3) << 2);
      sx[(nn * 4 + 0) * 20 + tp] = d0;
      sx[(nn * 4 + 1) * 20 + tp] = d1;
      sx[(nn * 4 + 2) * 20 + tp] = d2;
      sx[(nn * 4 + 3) * 20 + tp] = d3;
    }
    // ---- influence-weight A fragment from precomputed f16 rdiff
    const ushort* rp = rdiff + ((size_t)n * NBH + q * 8) * 3;
    uint4 r0 = *reinterpret_cast<const uint4*>(rp);
    uint4 r1 = *reinterpret_cast<const uint4*>(rp + 8);
    uint4 r2 = *reinterpret_cast<const uint4*>(rp + 16);
    uint wv[12] = {r0.x, r0.y, r0.z, r0.w, r1.x, r1.y, r1.z, r1.w, r2.x, r2.y, r2.z, r2.w};
    float wgt[8];
#pragma unroll
    for (int j = 0; j < 8; ++j) {
      int i0 = 3 * j, i1 = 3 * j + 1, i2 = 3 * j + 2;
      float rx = h2f((i0 & 1) ? (ushort)(wv[i0 >> 1] >> 16) : (ushort)(wv[i0 >> 1] & 0xFFFF));
      float ry = h2f((i1 & 1) ? (ushort)(wv[i1 >> 1] >> 16) : (ushort)(wv[i1 >> 1] & 0xFFFF));
      float rz = h2f((i2 & 1) ? (ushort)(wv[i2 >> 1] >> 16) : (ushort)(wv[i2 >> 1] & 0xFFFF));
      float dx = rx - kpx, dy = ry - kpy, dz = rz - kpz;
      float dist = sqrtf(dx * dx + dy * dy + dz * dz);
      float t = fmaxf(1.0f - dist * (1.0f / INFL), 0.0f);
      wgt[j] = (nn == 15) ? 0.f : t;
    }
    U8 af;
#pragma unroll
    for (int j2 = 0; j2 < 4; ++j2) af.u[j2] = packbf(wgt[2 * j2], wgt[2 * j2 + 1]);
    // ---- stage-1 MFMA: fk[kpt][d] = sum_h w[h][kpt] * x[h][d]
    int m = w * 4 + p;
#pragma unroll
    for (int c = 0; c < 4; ++c) {
      int d = c * 16 + nn;
      int db3 = nn >> 2;
      U8 bf;
      bf.v = *reinterpret_cast<const uint4*>(&sx[d * 20 + ((q ^ db3) << 2)]);
      f32x4 acc = __builtin_amdgcn_mfma_f32_16x16x32_bf16(af.s, bf.s,
                                                          (f32x4){0.f, 0.f, 0.f, 0.f}, 0, 0, 0);
#pragma unroll
      for (int r = 0; r < 4; ++r) {
        int kpt = q * 4 + r;
        if (kpt < 15) {
          int kap = kpt * 64 + d;
          int ch = kap >> 5, t2 = kap & 31;
          int tp2 = t2 ^ (((ch >> 3) & 3) << 3);
          s_fk[ch * 512 + m * 32 + tp2] = f2b(acc[r]);
        }
      }
    }
  }
  __syncthreads();

  // ---- stage-2: Y2[16x64] = FK[16x960] * kw; wave w owns col tile w
  f32x4 acc2 = (f32x4){0.f, 0.f, 0.f, 0.f};
  for (int ch = 0; ch < 30; ++ch) {
    int key = (ch >> 3) & 3;
    U8 a, b;
    a.v = *reinterpret_cast<const uint4*>(&s_fk[ch * 512 + nn * 32 + ((q ^ key) << 3)]);
    b.v = *reinterpret_cast<const uint4*>(kws + (size_t)ch * 2048 + w * 512 + nn * 32 + q * 8);
    acc2 = __builtin_amdgcn_mfma_f32_16x16x32_bf16(a.s, b.s, acc2, 0, 0, 0);
  }
  {
    int e = w * 16 + nn;
    int ch2 = e >> 5, t = e & 31;
#pragma unroll
    for (int r = 0; r < 4; ++r) {
      int mm = q * 4 + r;
      int tp = t ^ (((mm >> 2) & 3) << 3);
      s_y2[ch2 * 512 + mm * 32 + tp] = f2b(acc2[r]);
    }
  }
  __syncthreads();

  // ---- unary_2: Y3[16x256] = Y2 * W2; wave w owns col tiles w*4..w*4+3
  U8 a0, a1;
  {
    int key = (nn >> 2) & 3;
    a0.v = *reinterpret_cast<const uint4*>(&s_y2[0 * 512 + nn * 32 + ((q ^ key) << 3)]);
    a1.v = *reinterpret_cast<const uint4*>(&s_y2[1 * 512 + nn * 32 + ((q ^ key) << 3)]);
  }
#pragma unroll
  for (int t4 = 0; t4 < 4; ++t4) {
    int ct = w * 4 + t4;
    U8 b0, b1;
    b0.v = *reinterpret_cast<const uint4*>(w2s + (0 * 16 + ct) * 512 + nn * 32 + q * 8);
    b1.v = *reinterpret_cast<const uint4*>(w2s + (1 * 16 + ct) * 512 + nn * 32 + q * 8);
    f32x4 a = __builtin_amdgcn_mfma_f32_16x16x32_bf16(a0.s, b0.s, (f32x4){0.f, 0.f, 0.f, 0.f}, 0, 0, 0);
    a = __builtin_amdgcn_mfma_f32_16x16x32_bf16(a1.s, b1.s, a, 0, 0, 0);
#pragma unroll
    for (int r = 0; r < 4; ++r)
      Y3b[(size_t)(n_base + q * 4 + r) * 256 + ct * 16 + nn] = f2b(a[r]);
  }
}

// ---------------- final: out = leaky(bn(Y3b)) + bn(YSCb), f32 out
__global__ __launch_bounds__(256) void k_final(const ushort* __restrict__ Y3,
                                               const ushort* __restrict__ YSC,
                                               const float* __restrict__ s3,
                                               const float* __restrict__ ss3,
                                               const float* __restrict__ g2,
                                               const float* __restrict__ b2,
                                               const float* __restrict__ ssc,
                                               const float* __restrict__ sssc,
                                               const float* __restrict__ gsc,
                                               const float* __restrict__ bsc,
                                               float* __restrict__ out) {
  __shared__ float sc3[256], sh3[256], scc[256], shc[256];
  int tid = threadIdx.x;
  {
    float m = s3[tid] * (1.0f / NPTS);
    float v = ss3[tid] * (1.0f / NPTS) - m * m;
    float s = g2[tid] * rsqrtf(v + EPS);
    sc3[tid] = s;
    sh3[tid] = b2[tid] - m * s;
    m = ssc[tid] * (1.0f / NPTS);
    v = sssc[tid] * (1.0f / NPTS) - m * m;
    s = gsc[tid] * rsqrtf(v + EPS);
    scc[tid] = s;
    shc[tid] = bsc[tid] - m * s;
  }
  __syncthreads();
  const int units = NPTS * 32;  // short8 units per matrix
  int stride = gridDim.x * 256;
  for (int i = blockIdx.x * 256 + tid; i < units; i += stride) {
    short8 a = reinterpret_cast<const short8*>(Y3)[i];
    short8 b = reinterpret_cast<const short8*>(YSC)[i];
    int cb = (i & 31) * 8;
    float o[8];
#pragma unroll
    for (int k = 0; k < 8; ++k) {
      float x = b2f((ushort)a[k]) * sc3[cb + k] + sh3[cb + k];
      x = x > 0.f ? x : SLOPE * x;
      o[k] = x + b2f((ushort)b[k]) * scc[cb + k] + shc[cb + k];
    }
    float4* O4 = reinterpret_cast<float4*>(out + (size_t)i * 8);
    O4[0] = make_float4(o[0], o[1], o[2], o[3]);
    O4[1] = make_float4(o[4], o[5], o[6], o[7]);
  }
}

extern "C" void kernel_launch(void* const* d_in, const int* in_sizes, int n_in,
                              void* d_out, int out_size, void* d_ws, size_t ws_size,
                              hipStream_t stream) {
  const float* feats = (const float*)d_in[0];
  const float* xyz   = (const float*)d_in[1];
  const int* nidx    = (const int*)d_in[3];
  const float* W1    = (const float*)d_in[4];
  const float* g1    = (const float*)d_in[5];
  const float* b1    = (const float*)d_in[6];
  const float* kpp   = (const float*)d_in[7];
  const float* kw    = (const float*)d_in[8];
  const float* W2    = (const float*)d_in[9];
  const float* g2    = (const float*)d_in[10];
  const float* b2    = (const float*)d_in[11];
  const float* Wsc   = (const float*)d_in[12];
  const float* gsc   = (const float*)d_in[13];
  const float* bsc   = (const float*)d_in[14];
  float* out = (float*)d_out;

  // ws layout (bytes): X1r 10.24M | X1b 10.24M | Y3b 40.96M | YSCb 40.96M | rdiff 15.36M | weights | stats
  char* ws = (char*)d_ws;
  ushort* X1r   = (ushort*)ws;
  ushort* X1b   = (ushort*)(ws + 10240000);
  ushort* Y3b   = (ushort*)(ws + 20480000);
  ushort* YSCb  = (ushort*)(ws + 61440000);
  ushort* rdiff = (ushort*)(ws + 102400000);
  ushort* w1s   = (ushort*)(ws + 117760000);
  ushort* w2s   = (ushort*)(ws + 117776384);
  ushort* wscs  = (ushort*)(ws + 117809152);
  ushort* kws   = (ushort*)(ws + 117874688);
  float*  ST    = (float*)(ws + 117997568);
  float *S1 = ST, *SS1 = ST + 64;
  float *S3 = ST + 128, *SS3 = ST + 384;
  float *SSC = ST + 640, *SSSC = ST + 896;

  hipMemsetAsync(ST, 0, 1152 * sizeof(float), stream);
  k_prep<<<4096, 256, 0, stream>>>(xyz, nidx, W1, W2, Wsc, kw, rdiff, w1s, w2s, wscs, kws);
  // unary_1
  k_gemm_f32a<64><<<1250, 256, 0, stream>>>(feats, w1s, X1r, 128);
  k_colstats_b16<<<256, 256, 0, stream>>>(X1r, NPTS * 8, 64, S1, SS1);
  k_normb<<<512, 256, 0, stream>>>(X1r, S1, SS1, g1, b1, X1b);
  // shortcut
  k_gemm_f32a<256><<<1250, 256, 0, stream>>>(feats, wscs, YSCb, 128);
  k_colstats_b16<<<256, 256, 0, stream>>>(YSCb, NPTS * 32, 256, SSC, SSSC);
  // fused KPConv + unary_2
  k_kpfused<<<NPTS / 16, 256, 0, stream>>>(X1b, rdiff, nidx, kpp, kws, w2s, Y3b);
  k_colstats_b16<<<256, 256, 0, stream>>>(Y3b, NPTS * 32, 256, S3, SS3);
  // out = leaky(bn(Y3b)) + bn(YSCb)
  k_final<<<1024, 256, 0, stream>>>(Y3b, YSCb, S3, SS3, g2, b2, SSC, SSSC, gsc, bsc, out);
}